// Round 4
// baseline (306.073 us; speedup 1.0000x reference)
//
#include <hip/hip_runtime.h>
#include <math.h>

// MultiTaskGNN: 2-layer GAT + BN + ELU + two heads. N=50000, E=400000.
// R4: precomputed edge weights (no exp/shuffles in agg loops), 3-stage
// pipelined gathers, x-cast fused into gemm1, merged prep dispatch.

typedef unsigned short ushort_t;
typedef __attribute__((ext_vector_type(8))) unsigned short ushort8;
typedef __attribute__((ext_vector_type(4))) unsigned short ushort4v;
typedef __attribute__((ext_vector_type(8))) short short8;
typedef __attribute__((ext_vector_type(4))) float f32x4;

__device__ __forceinline__ ushort_t f2bf(float f) {  // RNE
  unsigned u = __float_as_uint(f);
  unsigned r = u + 0x7fffu + ((u >> 16) & 1u);
  return (ushort_t)(r >> 16);
}
__device__ __forceinline__ float bf2f(ushort_t h) {
  return __uint_as_float((unsigned)h << 16);
}
__device__ __forceinline__ float leaky02(float x) { return x >= 0.f ? x : 0.2f * x; }

__device__ __forceinline__ float wave_sum(float v) {
#pragma unroll
  for (int o = 1; o < 64; o <<= 1) v += __shfl_xor(v, o, 64);
  return v;
}
__device__ __forceinline__ int wave_incl_scan(int v, int lane) {
#pragma unroll
  for (int off = 1; off < 64; off <<= 1) {
    int t = __shfl_up(v, off, 64);
    if (lane >= off) v += t;
  }
  return v;
}

__device__ __forceinline__ void gld_lds16(const ushort_t* g, ushort_t* l) {
  __builtin_amdgcn_global_load_lds(
      (const __attribute__((address_space(1))) unsigned int*)g,
      (__attribute__((address_space(3))) unsigned int*)l, 16, 0, 0);
}

// ---------------- prep: zero counters + transpose-cast weights ----------------
__global__ void prep_kernel(int* __restrict__ counts, int* __restrict__ cursor,
                            const float* __restrict__ W1, const float* __restrict__ W2,
                            ushort_t* __restrict__ W1t, ushort_t* __restrict__ W2t, int N) {
  int i = blockIdx.x * 256 + threadIdx.x;
  if (i < N) {
    counts[i] = 0;
    cursor[i] = 0;
    return;
  }
  int j = i - N;
  if (j < 256 * 256) {
    int k = j >> 8, n2 = j & 255;
    W1t[n2 * 256 + k] = f2bf(W1[j]);
    return;
  }
  j -= 256 * 256;
  if (j < 256 * 64) {
    int k = j >> 6, n2 = j & 63;
    W2t[n2 * 256 + k] = f2bf(W2[j]);
  }
}

// ---------------- graph build ----------------
__global__ void hist_kernel(const int* __restrict__ dst, int* __restrict__ counts, int E) {
  int e = blockIdx.x * blockDim.x + threadIdx.x;
  if (e < E) atomicAdd(&counts[dst[e]], 1);
}

__global__ __launch_bounds__(256) void scan_chunks_kernel(const int* __restrict__ counts,
                                                          int* __restrict__ offsets,
                                                          int* __restrict__ partials, int N) {
  __shared__ int ws[4];
  int tid = threadIdx.x, lane = tid & 63, wv = tid >> 6;
  int i = blockIdx.x * 256 + tid;
  int v = (i < N) ? counts[i] : 0;
  int incl = wave_incl_scan(v, lane);
  if (lane == 63) ws[wv] = incl;
  __syncthreads();
  int wbase = 0;
  for (int k = 0; k < wv; ++k) wbase += ws[k];
  if (i < N) offsets[i] = wbase + incl - v;
  if (tid == 255) partials[blockIdx.x] = wbase + incl;
}

__global__ __launch_bounds__(256) void scan_partials_kernel(const int* __restrict__ partials,
                                                            int* __restrict__ pprefix, int nb) {
  __shared__ int ws[4];
  int tid = threadIdx.x, lane = tid & 63, wv = tid >> 6;
  int v = (tid < nb) ? partials[tid] : 0;
  int incl = wave_incl_scan(v, lane);
  if (lane == 63) ws[wv] = incl;
  __syncthreads();
  int wbase = 0;
  for (int k = 0; k < wv; ++k) wbase += ws[k];
  if (tid < nb) pprefix[tid] = wbase + incl - v;
  if (tid == 255) pprefix[nb] = wbase + incl;
}

__global__ void add_base_kernel(int* __restrict__ offsets, const int* __restrict__ pprefix,
                                int N, int nb) {
  int i = blockIdx.x * 256 + threadIdx.x;
  if (i < N) offsets[i] += pprefix[blockIdx.x];
  if (i == 0) offsets[N] = pprefix[nb];
}

__global__ void scatter_kernel(const int* __restrict__ src, const int* __restrict__ dst,
                               const int* __restrict__ offsets, int* __restrict__ cursor,
                               int* __restrict__ csr_src, int* __restrict__ csr_dst, int E) {
  int e = blockIdx.x * blockDim.x + threadIdx.x;
  if (e < E) {
    int d = dst[e];
    int p = atomicAdd(&cursor[d], 1);
    int pos = offsets[d] + p;
    csr_src[pos] = src[e];
    csr_dst[pos] = d;
  }
}

// ---------------- edge weights (layer 1: 4 heads; + self weights) ----------------
__global__ void edge_weights1(const int* __restrict__ csr_src, const int* __restrict__ csr_dst,
                              const float* __restrict__ as1, const float* __restrict__ ad1,
                              float* __restrict__ we, float* __restrict__ wself, int E, int N) {
  int t = blockIdx.x * 256 + threadIdx.x;
  if (t < E) {
    int s = csr_src[t], d = csr_dst[t];
    float4 a = *(const float4*)&as1[s * 4];
    float4 b = *(const float4*)&ad1[d * 4];
    float4 o;
    o.x = __expf(leaky02(a.x + b.x));
    o.y = __expf(leaky02(a.y + b.y));
    o.z = __expf(leaky02(a.z + b.z));
    o.w = __expf(leaky02(a.w + b.w));
    *(float4*)&we[(size_t)t * 4] = o;
  } else if (t < E + N) {
    int n = t - E;
    float4 a = *(const float4*)&as1[n * 4];
    float4 b = *(const float4*)&ad1[n * 4];
    float4 o;
    o.x = __expf(leaky02(a.x + b.x));
    o.y = __expf(leaky02(a.y + b.y));
    o.z = __expf(leaky02(a.z + b.z));
    o.w = __expf(leaky02(a.w + b.w));
    *(float4*)&wself[n * 4] = o;
  }
}

// ---------------- edge weights (layer 2: 1 head; + self weights) ----------------
__global__ void edge_weights2(const int* __restrict__ csr_src, const int* __restrict__ csr_dst,
                              const float* __restrict__ as2, const float* __restrict__ ad2,
                              float* __restrict__ we, float* __restrict__ wself, int E, int N) {
  int t = blockIdx.x * 256 + threadIdx.x;
  if (t < E) {
    we[t] = __expf(leaky02(as2[csr_src[t]] + ad2[csr_dst[t]]));
  } else if (t < E + N) {
    int n = t - E;
    wself[n] = __expf(leaky02(as2[n] + ad2[n]));
  }
}

// ---------------- MFMA bf16 GEMM + fused alpha epilogue ----------------
// C[M,Nt] = A[M,K] @ Bt[Nt,K]^T, bf16 out. WM waves, BM=32*WM rows, 64 cols/block.
// CASTA: A is fp32, converted in-register during staging.
template <int WM, bool CASTA>
__global__ __launch_bounds__(WM * 64) void mfma_gemm_fused(
    const void* __restrict__ Ain, const ushort_t* __restrict__ Bt,
    ushort_t* __restrict__ C, const float* __restrict__ avs, const float* __restrict__ avd,
    float* __restrict__ as_out, float* __restrict__ ad_out, int M, int Nt, int K, int H) {
  constexpr int BM = WM * 32;
  constexpr int NB = 4 / WM;
  __shared__ ushort_t As[BM * 32];
  __shared__ ushort_t Bs[64 * 32];
  const int t = threadIdx.x;
  const int w = t >> 6, l = t & 63;
  const int m0 = blockIdx.y * BM;
  const int n0 = blockIdx.x * 64;
  const int head = n0 >> 6;

  f32x4 zero4 = {0.f, 0.f, 0.f, 0.f};
  f32x4 acc[2][4];
#pragma unroll
  for (int i = 0; i < 2; ++i)
#pragma unroll
    for (int j = 0; j < 4; ++j) acc[i][j] = zero4;

  // B staging (bf16, global_load_lds): wave-inst covers 16 rows x 32 cols
  const int scol = (l & 3) * 8;
  const ushort_t* Bgb[NB];
  ushort_t* Bsl[NB];
#pragma unroll
  for (int b = 0; b < NB; ++b) {
    int r = (b * WM + w) * 16 + (l >> 2);
    Bgb[b] = Bt + (size_t)(n0 + r) * K + scol;
    Bsl[b] = &Bs[(b * WM + w) * 512];
  }
  // A staging
  const ushort_t* Aga[2];
  ushort_t* Asl[2];
  const float* Axg = nullptr;
  ushort_t* AsWc = nullptr;
  if (CASTA) {
    int ar = t >> 1, ac = (t & 1) * 16;
    Axg = (const float*)Ain + (size_t)min(m0 + ar, M - 1) * K + ac;
    AsWc = &As[ar * 32 + ac];
  } else {
#pragma unroll
    for (int a = 0; a < 2; ++a) {
      int r = (a * WM + w) * 16 + (l >> 2);
      int gr = min(m0 + r, M - 1);
      Aga[a] = (const ushort_t*)Ain + (size_t)gr * K + scol;
      Asl[a] = &As[(a * WM + w) * 512];
    }
  }

  for (int k0 = 0; k0 < K; k0 += 32) {
    if (CASTA) {
      float4 f0 = *(const float4*)(Axg + k0);
      float4 f1 = *(const float4*)(Axg + k0 + 4);
      float4 f2 = *(const float4*)(Axg + k0 + 8);
      float4 f3 = *(const float4*)(Axg + k0 + 12);
      __syncthreads();
#pragma unroll
      for (int b = 0; b < NB; ++b) gld_lds16(Bgb[b] + k0, Bsl[b]);
      ushort8 u0, u1;
      u0[0] = f2bf(f0.x); u0[1] = f2bf(f0.y); u0[2] = f2bf(f0.z); u0[3] = f2bf(f0.w);
      u0[4] = f2bf(f1.x); u0[5] = f2bf(f1.y); u0[6] = f2bf(f1.z); u0[7] = f2bf(f1.w);
      u1[0] = f2bf(f2.x); u1[1] = f2bf(f2.y); u1[2] = f2bf(f2.z); u1[3] = f2bf(f2.w);
      u1[4] = f2bf(f3.x); u1[5] = f2bf(f3.y); u1[6] = f2bf(f3.z); u1[7] = f2bf(f3.w);
      *(ushort8*)AsWc = u0;
      *(ushort8*)(AsWc + 8) = u1;
      __syncthreads();
    } else {
      __syncthreads();
#pragma unroll
      for (int a = 0; a < 2; ++a) gld_lds16(Aga[a] + k0, Asl[a]);
#pragma unroll
      for (int b = 0; b < NB; ++b) gld_lds16(Bgb[b] + k0, Bsl[b]);
      __syncthreads();
    }
    const int kq = (l >> 4) * 8;
    short8 af[2], bfr[4];
#pragma unroll
    for (int i = 0; i < 2; ++i)
      af[i] = *(const short8*)&As[(w * 32 + i * 16 + (l & 15)) * 32 + kq];
#pragma unroll
    for (int j = 0; j < 4; ++j)
      bfr[j] = *(const short8*)&Bs[(j * 16 + (l & 15)) * 32 + kq];
#pragma unroll
    for (int i = 0; i < 2; ++i)
#pragma unroll
      for (int j = 0; j < 4; ++j)
        acc[i][j] = __builtin_amdgcn_mfma_f32_16x16x32_bf16(af[i], bfr[j], acc[i][j], 0, 0, 0);
  }

  const int rbase = m0 + w * 32 + (l >> 4) * 4;
  const int cbase = n0 + (l & 15);
#pragma unroll
  for (int i = 0; i < 2; ++i)
#pragma unroll
    for (int j = 0; j < 4; ++j)
#pragma unroll
      for (int r = 0; r < 4; ++r) {
        int row = rbase + i * 16 + r;
        if (row < M) C[(size_t)row * Nt + cbase + j * 16] = f2bf(acc[i][j][r]);
      }

  // fused alphas over this head's 64 cols
  float asw[4], adw[4];
#pragma unroll
  for (int j = 0; j < 4; ++j) {
    asw[j] = avs[head * 64 + (l & 15) + j * 16];
    adw[j] = avd[head * 64 + (l & 15) + j * 16];
  }
#pragma unroll
  for (int i = 0; i < 2; ++i)
#pragma unroll
    for (int r = 0; r < 4; ++r) {
      float s_ = acc[i][0][r] * asw[0] + acc[i][1][r] * asw[1] +
                 acc[i][2][r] * asw[2] + acc[i][3][r] * asw[3];
      float d_ = acc[i][0][r] * adw[0] + acc[i][1][r] * adw[1] +
                 acc[i][2][r] * adw[2] + acc[i][3][r] * adw[3];
#pragma unroll
      for (int o = 1; o < 16; o <<= 1) {
        s_ += __shfl_xor(s_, o, 64);
        d_ += __shfl_xor(d_, o, 64);
      }
      if ((l & 15) == 0) {
        int row = rbase + i * 16 + r;
        if (row < M) {
          as_out[(size_t)row * H + head] = s_;
          ad_out[(size_t)row * H + head] = d_;
        }
      }
    }
}

// ---------------- layer 1 agg: precomputed weights, 2 edges/iter, 3-stage pipe ----------------
__global__ __launch_bounds__(256) void agg1_kernel(
    const ushort_t* __restrict__ h1, const int* __restrict__ offsets,
    const int* __restrict__ csr, const float* __restrict__ we,
    const float* __restrict__ wself, const float* __restrict__ b1,
    const float* __restrict__ bnw, const float* __restrict__ bnb,
    const float* __restrict__ bnm, const float* __restrict__ bnv,
    ushort_t* __restrict__ out, int N) {
  int n = blockIdx.x * 4 + (threadIdx.x >> 6);
  int l = threadIdx.x & 63;
  if (n >= N) return;
  const int g = l >> 5, ll = l & 31, hh = ll >> 3;
  int off = offsets[n], deg = offsets[n + 1] - off;
  float acc[8] = {0, 0, 0, 0, 0, 0, 0, 0};
  float ds[4] = {0, 0, 0, 0};

  for (int base = 0; base < deg; base += 64) {
    int cnt = min(64, deg - base);
    if (l < cnt) {
      float4 w4 = *(const float4*)&we[(size_t)(off + base + l) * 4];
      ds[0] += w4.x; ds[1] += w4.y; ds[2] += w4.z; ds[3] += w4.w;
    }
    // group g handles edges j+g; clamped loads + zeroed weights for tails
    int e0 = off + base + min(g, cnt - 1);
    int s_c = csr[e0];
    float w_c = we[(size_t)e0 * 4 + hh];
    if (g >= cnt) w_c = 0.f;
    ushort8 hv_c = *(const ushort8*)&h1[(size_t)s_c * 256 + ll * 8];
    int s_n = 0; float w_n = 0.f;
    if (cnt > 2) {
      int e1 = off + base + min(2 + g, cnt - 1);
      s_n = csr[e1];
      w_n = we[(size_t)e1 * 4 + hh];
      if (2 + g >= cnt) w_n = 0.f;
    }
    for (int j = 2; j < cnt; j += 2) {
      int s_f = 0; float w_f = 0.f;
      if (j + 2 < cnt) {
        int ef = off + base + min(j + 2 + g, cnt - 1);
        s_f = csr[ef];
        w_f = we[(size_t)ef * 4 + hh];
        if (j + 2 + g >= cnt) w_f = 0.f;
      }
      ushort8 hv_n = *(const ushort8*)&h1[(size_t)s_n * 256 + ll * 8];
#pragma unroll
      for (int k = 0; k < 8; ++k) acc[k] = fmaf(w_c, bf2f(hv_c[k]), acc[k]);
      s_c = s_n; w_c = w_n; hv_c = hv_n; s_n = s_f; w_n = w_f;
    }
#pragma unroll
    for (int k = 0; k < 8; ++k) acc[k] = fmaf(w_c, bf2f(hv_c[k]), acc[k]);
  }
  // cross-group reduce
#pragma unroll
  for (int k = 0; k < 8; ++k) acc[k] += __shfl_xor(acc[k], 32, 64);
  float den[4];
#pragma unroll
  for (int h = 0; h < 4; ++h) den[h] = wave_sum(ds[h]);
  // self loop
  float4 ws4 = *(const float4*)&wself[n * 4];
  float wsf[4] = {ws4.x, ws4.y, ws4.z, ws4.w};
#pragma unroll
  for (int h = 0; h < 4; ++h) den[h] += wsf[h];
  ushort8 hvn = *(const ushort8*)&h1[(size_t)n * 256 + ll * 8];
  float wsh = wsf[hh];
#pragma unroll
  for (int k = 0; k < 8; ++k) acc[k] = fmaf(wsh, bf2f(hvn[k]), acc[k]);
  // BN + ELU + store (group g stores features c0..c0+3)
  float inv_den = 1.f / (den[hh] + 1e-16f);
  int c0 = ll * 8 + g * 4;
  float4 bb = *(const float4*)&b1[c0];
  float4 bw = *(const float4*)&bnw[c0];
  float4 bbb = *(const float4*)&bnb[c0];
  float4 bm = *(const float4*)&bnm[c0];
  float4 bv = *(const float4*)&bnv[c0];
  float bbf[4] = {bb.x, bb.y, bb.z, bb.w};
  float bwf[4] = {bw.x, bw.y, bw.z, bw.w};
  float bbbf[4] = {bbb.x, bbb.y, bbb.z, bbb.w};
  float bmf[4] = {bm.x, bm.y, bm.z, bm.w};
  float bvf[4] = {bv.x, bv.y, bv.z, bv.w};
  ushort4v o4;
#pragma unroll
  for (int q = 0; q < 4; ++q) {
    float o = acc[g * 4 + q] * inv_den + bbf[q];
    o = (o - bmf[q]) * rsqrtf(bvf[q] + 1e-5f) * bwf[q] + bbbf[q];
    o = o > 0.f ? o : expm1f(o);
    o4[q] = f2bf(o);
  }
  *(ushort4v*)&out[(size_t)n * 256 + c0] = o4;
}

// ---------------- layer 2 agg: 4 edges/iter, 3-stage pipe, fused heads ----------------
__global__ __launch_bounds__(256) void agg2_kernel(
    const ushort_t* __restrict__ h2, const int* __restrict__ offsets,
    const int* __restrict__ csr, const float* __restrict__ we,
    const float* __restrict__ wself, const float* __restrict__ b2,
    const float* __restrict__ bnw, const float* __restrict__ bnb,
    const float* __restrict__ bnm, const float* __restrict__ bnv,
    const float* __restrict__ Wr, const float* __restrict__ br,
    const float* __restrict__ Wc, const float* __restrict__ bc,
    float* __restrict__ out_reg, float* __restrict__ out_clf, int N) {
  int n = blockIdx.x * 4 + (threadIdx.x >> 6);
  int l = threadIdx.x & 63;
  if (n >= N) return;
  const int g = l >> 4, ll = l & 15;
  int off = offsets[n], deg = offsets[n + 1] - off;
  float acc[4] = {0, 0, 0, 0};
  float ds = 0.f;

  for (int base = 0; base < deg; base += 64) {
    int cnt = min(64, deg - base);
    if (l < cnt) ds += we[off + base + l];
    int e0 = off + base + min(g, cnt - 1);
    int s_c = csr[e0];
    float w_c = we[e0];
    if (g >= cnt) w_c = 0.f;
    ushort4v hv_c = *(const ushort4v*)&h2[(size_t)s_c * 64 + ll * 4];
    int s_n = 0; float w_n = 0.f;
    if (cnt > 4) {
      int e1 = off + base + min(4 + g, cnt - 1);
      s_n = csr[e1];
      w_n = we[e1];
      if (4 + g >= cnt) w_n = 0.f;
    }
    for (int j = 4; j < cnt; j += 4) {
      int s_f = 0; float w_f = 0.f;
      if (j + 4 < cnt) {
        int ef = off + base + min(j + 4 + g, cnt - 1);
        s_f = csr[ef];
        w_f = we[ef];
        if (j + 4 + g >= cnt) w_f = 0.f;
      }
      ushort4v hv_n = *(const ushort4v*)&h2[(size_t)s_n * 64 + ll * 4];
#pragma unroll
      for (int k = 0; k < 4; ++k) acc[k] = fmaf(w_c, bf2f(hv_c[k]), acc[k]);
      s_c = s_n; w_c = w_n; hv_c = hv_n; s_n = s_f; w_n = w_f;
    }
#pragma unroll
    for (int k = 0; k < 4; ++k) acc[k] = fmaf(w_c, bf2f(hv_c[k]), acc[k]);
  }
#pragma unroll
  for (int k = 0; k < 4; ++k) {
    acc[k] += __shfl_xor(acc[k], 16, 64);
    acc[k] += __shfl_xor(acc[k], 32, 64);
  }
  float den = wave_sum(ds);
  float ws = wself[n];
  den += ws;
  ushort4v hvn = *(const ushort4v*)&h2[(size_t)n * 64 + ll * 4];
#pragma unroll
  for (int k = 0; k < 4; ++k) acc[k] = fmaf(ws, bf2f(hvn[k]), acc[k]);

  float inv_den = 1.f / (den + 1e-16f);
  int c0 = ll * 4;
  float4 bb = *(const float4*)&b2[c0];
  float4 bw = *(const float4*)&bnw[c0];
  float4 bbb = *(const float4*)&bnb[c0];
  float4 bm = *(const float4*)&bnm[c0];
  float4 bv = *(const float4*)&bnv[c0];
  float4 wr = *(const float4*)&Wr[c0];
  float4 wc = *(const float4*)&Wc[c0];
  float bbf[4] = {bb.x, bb.y, bb.z, bb.w};
  float bwf[4] = {bw.x, bw.y, bw.z, bw.w};
  float bbbf[4] = {bbb.x, bbb.y, bbb.z, bbb.w};
  float bmf[4] = {bm.x, bm.y, bm.z, bm.w};
  float bvf[4] = {bv.x, bv.y, bv.z, bv.w};
  float wrf[4] = {wr.x, wr.y, wr.z, wr.w};
  float wcf[4] = {wc.x, wc.y, wc.z, wc.w};
  float rs = 0.f, cs = 0.f;
#pragma unroll
  for (int q = 0; q < 4; ++q) {
    float o = acc[q] * inv_den + bbf[q];
    o = (o - bmf[q]) * rsqrtf(bvf[q] + 1e-5f) * bwf[q] + bbbf[q];
    o = o > 0.f ? o : expm1f(o);
    rs = fmaf(o, wrf[q], rs);
    cs = fmaf(o, wcf[q], cs);
  }
  float rsum = wave_sum(rs) * 0.25f;
  float csum = wave_sum(cs) * 0.25f;
  if (l == 0) {
    out_reg[n] = rsum + br[0];
    float z = csum + bc[0];
    out_clf[n] = 1.f / (1.f + __expf(-z));
  }
}

// ---------------- launcher ----------------
extern "C" void kernel_launch(void* const* d_in, const int* in_sizes, int n_in,
                              void* d_out, int out_size, void* d_ws, size_t ws_size,
                              hipStream_t stream) {
  const float* x      = (const float*)d_in[0];
  const int*   ei     = (const int*)d_in[1];
  const float* W1     = (const float*)d_in[2];
  const float* a_src1 = (const float*)d_in[3];
  const float* a_dst1 = (const float*)d_in[4];
  const float* b1     = (const float*)d_in[5];
  const float* bn1w   = (const float*)d_in[6];
  const float* bn1b   = (const float*)d_in[7];
  const float* bn1m   = (const float*)d_in[8];
  const float* bn1v   = (const float*)d_in[9];
  const float* W2     = (const float*)d_in[10];
  const float* a_src2 = (const float*)d_in[11];
  const float* a_dst2 = (const float*)d_in[12];
  const float* b2     = (const float*)d_in[13];
  const float* bn2w   = (const float*)d_in[14];
  const float* bn2b   = (const float*)d_in[15];
  const float* bn2m   = (const float*)d_in[16];
  const float* bn2v   = (const float*)d_in[17];
  const float* Wr     = (const float*)d_in[18];
  const float* br     = (const float*)d_in[19];
  const float* Wc     = (const float*)d_in[20];
  const float* bc     = (const float*)d_in[21];

  const int N = in_sizes[0] / 256;  // 50000
  const int E = in_sizes[1] / 2;    // 400000
  const int* srcv = ei;
  const int* dstv = ei + E;

  char* w = (char*)d_ws;
  auto alloc = [&](size_t bytes) {
    char* p = w;
    w += (bytes + 255) & ~(size_t)255;
    return p;
  };
  const int nb = (N + 255) / 256;
  int* counts    = (int*)alloc((size_t)N * 4);
  int* cursor    = (int*)alloc((size_t)N * 4);
  int* offsets   = (int*)alloc((size_t)(N + 1) * 4);
  int* partials  = (int*)alloc((size_t)nb * 4);
  int* pprefix   = (int*)alloc((size_t)(nb + 1) * 4);
  int* csr_src   = (int*)alloc((size_t)E * 4);
  int* csr_dst   = (int*)alloc((size_t)E * 4);
  float* as1     = (float*)alloc((size_t)N * 4 * 4);
  float* ad1     = (float*)alloc((size_t)N * 4 * 4);
  float* as2     = (float*)alloc((size_t)N * 4);
  float* ad2     = (float*)alloc((size_t)N * 4);
  float* we1     = (float*)alloc((size_t)E * 4 * 4);
  float* wself1  = (float*)alloc((size_t)N * 4 * 4);
  float* we2     = (float*)alloc((size_t)E * 4);
  float* wself2  = (float*)alloc((size_t)N * 4);
  ushort_t* W1t  = (ushort_t*)alloc((size_t)256 * 256 * 2);
  ushort_t* W2t  = (ushort_t*)alloc((size_t)64 * 256 * 2);
  ushort_t* h1b  = (ushort_t*)alloc((size_t)N * 256 * 2);
  ushort_t* h1a  = (ushort_t*)alloc((size_t)N * 256 * 2);
  ushort_t* h2b  = (ushort_t*)alloc((size_t)N * 64 * 2);

  float* out_reg = (float*)d_out;

  // prep: zero counters + weight transpose-casts (one dispatch)
  int prep_items = N + 256 * 256 + 256 * 64;
  prep_kernel<<<(prep_items + 255) / 256, 256, 0, stream>>>(counts, cursor, W1, W2, W1t, W2t, N);

  // graph build
  hist_kernel<<<(E + 255) / 256, 256, 0, stream>>>(dstv, counts, E);
  scan_chunks_kernel<<<nb, 256, 0, stream>>>(counts, offsets, partials, N);
  scan_partials_kernel<<<1, 256, 0, stream>>>(partials, pprefix, nb);
  add_base_kernel<<<nb, 256, 0, stream>>>(offsets, pprefix, N, nb);
  scatter_kernel<<<(E + 255) / 256, 256, 0, stream>>>(srcv, dstv, offsets, cursor,
                                                      csr_src, csr_dst, E);

  const int nwb = (N + 3) / 4;
  const int ewb = (E + N + 255) / 256;

  // layer 1
  dim3 g1(4, (N + 127) / 128);
  mfma_gemm_fused<4, true><<<g1, 256, 0, stream>>>(x, W1t, h1b, a_src1, a_dst1, as1, ad1,
                                                   N, 256, 256, 4);
  edge_weights1<<<ewb, 256, 0, stream>>>(csr_src, csr_dst, as1, ad1, we1, wself1, E, N);
  agg1_kernel<<<nwb, 256, 0, stream>>>(h1b, offsets, csr_src, we1, wself1, b1,
                                       bn1w, bn1b, bn1m, bn1v, h1a, N);

  // layer 2
  dim3 g2(1, (N + 63) / 64);
  mfma_gemm_fused<2, false><<<g2, 128, 0, stream>>>(h1a, W2t, h2b, a_src2, a_dst2, as2, ad2,
                                                    N, 64, 256, 1);
  edge_weights2<<<ewb, 256, 0, stream>>>(csr_src, csr_dst, as2, ad2, we2, wself2, E, N);
  agg2_kernel<<<nwb, 256, 0, stream>>>(h2b, offsets, csr_src, we2, wself2, b2,
                                       bn2w, bn2b, bn2m, bn2v, Wr, br, Wc, bc,
                                       out_reg, out_reg + N, N);
}